// Round 4
// baseline (676.085 us; speedup 1.0000x reference)
//
#include <hip/hip_runtime.h>
#include <hip/hip_fp16.h>

// Fern patch-descriptor pipeline, fully fused single kernel.
//   x:(64,8,128,128) f32, thresholds:(8,12) f32, table:(8,4096,32) f32,
//   chan_idx:(8,12,2) i32, offsets:(8,12,2,2) i32
//   out:(64, 32*114*114) f32
//
// R3: (a) explicit double-buffered table gathers (R2 disasm-inferred form was
// 8 serial vmcnt(0) L2 round-trips per position; VGPR=36 proved the compiler
// minimized regs instead of pipelining). (b) P-chain split depth 12->6.
// (c) phase 3 h-sums into the dead xs region (not in-place) -> 2x work items,
// half-length scan chains. LDS unchanged 79848 B -> 2 blocks/CU (20 waves).

#define NN 64
#define CC 8
#define HH 128
#define WW 128
#define MM 8
#define KK 12
#define DD 32
#define OUTS 114
#define TT 19          // output tile edge (114 = 6*19 exact)
#define PT 25          // position tile edge = TT + POOL - 1
#define XT 33          // x tile edge = PT + L - 1
#define XSTRIDE (XT*XT)   // 1089
#define VSTRIDE 36        // vote row stride in halves (72 B rows, 8B-aligned)
#define HSTRIDE 36        // h-sum row stride in halves
#define NPOSI (PT*PT)     // 625
#define THREADS 640
#define POOLW 7

#define LDS_BYTES (CC*XSTRIDE*4 + NPOSI*VSTRIDE*2)   // 34848 + 45000 = 79848

// 8-byte LDS accessors: 4 halves <-> float4
__device__ __forceinline__ float4 ld4h(const __half* p) {
    union { float2 f; __half2 h[2]; } u;
    u.f = *(const float2*)p;
    float2 a = __half22float2(u.h[0]);
    float2 b = __half22float2(u.h[1]);
    return make_float4(a.x, a.y, b.x, b.y);
}
__device__ __forceinline__ void st4h(__half* p, float4 v) {
    union { float2 f; __half2 h[2]; } u;
    u.h[0] = __floats2half2_rn(v.x, v.y);
    u.h[1] = __floats2half2_rn(v.z, v.w);
    *(float2*)p = u.f;
}

__global__ __launch_bounds__(THREADS, 5)   // 5 waves/EU -> VGPR<=102 -> 2 blocks/CU
void fern_fused(const float* __restrict__ x,
                const float* __restrict__ thresholds,
                const float* __restrict__ table,
                const int*   __restrict__ chan_idx,
                const int*   __restrict__ offsets,
                float* __restrict__ out)
{
    extern __shared__ float smem[];
    float*  xs = smem;                           // [8][33][33] f32 (phases 1-2)
    __half* vs = (__half*)(smem + CC*XSTRIDE);   // [625][36] f16 votes
    __half* hs = (__half*)smem;                  // [25*19][36] f16 h-sums (phase 3, reuses xs)

    const int tile = blockIdx.x;         // 0..2303
    const int n    = tile / 36;
    const int t2   = tile - n*36;
    const int ti   = t2 / 6;
    const int tj   = t2 - ti*6;
    const int i0   = ti * TT;            // 0..95
    const int j0   = tj * TT;

    const int tid = threadIdx.x;

    // ---------------- Phase 1: stage x tile into LDS ----------------
    // rows i0..i0+32 <= 127, cols j0..j0+32 <= 127 exactly: no clamping.
    const float* xn = x + (size_t)n * (CC*HH*WW);
    for (int idx = tid; idx < CC*XSTRIDE; idx += THREADS) {
        int c   = idx / XSTRIDE;
        int rem = idx - c*XSTRIDE;
        int r   = rem / XT;
        int col = rem - r*XT;
        xs[idx] = xn[(c*HH + (i0 + r))*WW + (j0 + col)];
    }
    __syncthreads();

    // ---------------- Phase 2: per-position fern votes into LDS ------------
    // 625 positions, 640 threads: one balanced pass.
    if (tid < NPOSI) {
        const int y  = tid / PT;
        const int j  = tid - y*PT;
        const int pb = y*XT + j;

        // --- words + confs (bits): per-fern, split product chains ---
        int   toff[MM];      // byte offset of fern row in table
        float confv[MM];
        #pragma unroll
        for (int m = 0; m < MM; ++m) {
            unsigned w = 0u;
            float Pa = 1.f, Pb = 1.f;        // split prod(1+e): depth 6
            #pragma unroll
            for (int k = 0; k < KK; ++k) {
                const int mk = m*KK + k;
                // compile-time mk -> wave-uniform scalar loads
                int c1  = chan_idx[mk*2 + 0];
                int c2  = chan_idx[mk*2 + 1];
                int dy1 = offsets[mk*4 + 0];
                int dx1 = offsets[mk*4 + 1];
                int dy2 = offsets[mk*4 + 2];
                int dx2 = offsets[mk*4 + 3];
                float thr = thresholds[mk];
                float p1 = xs[c1*XSTRIDE + dy1*XT + dx1 + pb];
                float p2 = xs[c2*XSTRIDE + dy2*XT + dx2 + pb];
                float z  = (p1 - p2) - thr;
                if (z > 0.f) w |= (1u << k);
                float e = __expf(-10.f * fabsf(z));
                if (k & 1) Pb += Pb * e; else Pa += Pa * e;
            }
            confv[m] = __builtin_amdgcn_rcpf(Pa * Pb);
            toff[m]  = (int)(((m << 12) + w) << 7);   // *(32 floats*4B)=128B rows
        }

        // --- gathers: double-buffered across d4 chunks (8 loads in flight
        //     while previous chunk's fmas consume) ---
        const char* tb = (const char*)table;
        float4 cur[MM];
        #pragma unroll
        for (int m = 0; m < MM; ++m)
            cur[m] = *(const float4*)(tb + toff[m]);

        __half* vrow = vs + tid*VSTRIDE;
        #pragma unroll
        for (int d4 = 0; d4 < DD/4; ++d4) {
            float4 nxt[MM];
            if (d4 < DD/4 - 1) {
                #pragma unroll
                for (int m = 0; m < MM; ++m)
                    nxt[m] = *(const float4*)(tb + toff[m] + (d4+1)*16);
            }
            float4 acc = make_float4(0.f, 0.f, 0.f, 0.f);
            #pragma unroll
            for (int m = 0; m < MM; ++m) {
                float c = confv[m];
                acc.x += c*cur[m].x; acc.y += c*cur[m].y;
                acc.z += c*cur[m].z; acc.w += c*cur[m].w;
            }
            st4h(vrow + d4*4, acc);
            if (d4 < DD/4 - 1) {
                #pragma unroll
                for (int m = 0; m < MM; ++m) cur[m] = nxt[m];
            }
        }
    }
    __syncthreads();

    // ------------- Phase 3a: horizontal 7-window sums vs -> hs --------------
    // item = (y, d4, half): 25*8*2 = 400 items, each scans <=16 cols.
    // half 0: j 0..15 -> jo 0..9 ; half 1: j 10..24 -> jo 10..18.
    for (int w = tid; w < PT*8*2; w += THREADS) {
        int y  = w >> 4;
        int r  = w & 15;
        int d4 = r >> 1;
        int h  = r & 1;
        int jbeg = h ? 10 : 0;
        int jend = h ? PT : 16;
        float4 s = make_float4(0.f, 0.f, 0.f, 0.f);
        float4 ring[POOLW];
        #pragma unroll
        for (int jj = 0; jj < 16; ++jj) {
            int j = jbeg + jj;
            if (j >= jend) break;
            float4 v = ld4h(vs + (y*PT + j)*VSTRIDE + d4*4);
            int step = jj;                     // steps since scan start
            if (step >= POOLW) {
                float4 o = ring[step % POOLW];
                s.x -= o.x; s.y -= o.y; s.z -= o.z; s.w -= o.w;
            }
            ring[step % POOLW] = v;
            s.x += v.x; s.y += v.y; s.z += v.z; s.w += v.w;
            if (step >= POOLW-1) {
                int jo = j - POOLW + 1;        // h=0: 0..9, h=1: 10..18
                st4h(hs + (y*TT + jo)*HSTRIDE + d4*4, s);
            }
        }
    }
    __syncthreads();

    // ---------------- Phase 3b: vertical 7-window + store -------------------
    // item = h*152 + d4*19 + jo (jo fastest within group for coalescing):
    // half 0: y 0..15 -> io 0..9 ; half 1: y 10..24 -> io 10..18.
    const float inv = 1.f / 49.f;
    float* outn = out + (size_t)n * (DD*OUTS*OUTS);
    for (int w = tid; w < 2*8*TT; w += THREADS) {
        int h  = w / 152;
        int r  = w - h*152;
        int d4 = r / TT;
        int jo = r - d4*TT;
        int ybeg = h ? 10 : 0;
        int yend = h ? PT : 16;
        float4 s = make_float4(0.f, 0.f, 0.f, 0.f);
        float4 ring[POOLW];
        #pragma unroll
        for (int yy = 0; yy < 16; ++yy) {
            int y = ybeg + yy;
            if (y >= yend) break;
            float4 v = ld4h(hs + (y*TT + jo)*HSTRIDE + d4*4);
            int step = yy;
            if (step >= POOLW) {
                float4 o = ring[step % POOLW];
                s.x -= o.x; s.y -= o.y; s.z -= o.z; s.w -= o.w;
            }
            ring[step % POOLW] = v;
            s.x += v.x; s.y += v.y; s.z += v.z; s.w += v.w;
            if (step >= POOLW-1) {
                int io = y - POOLW + 1;
                size_t base = ((size_t)(d4*4)*OUTS + (i0 + io))*OUTS + (j0 + jo);
                outn[base                      ] = s.x * inv;
                outn[base +   (size_t)OUTS*OUTS] = s.y * inv;
                outn[base + 2*(size_t)OUTS*OUTS] = s.z * inv;
                outn[base + 3*(size_t)OUTS*OUTS] = s.w * inv;
            }
        }
    }
}

extern "C" void kernel_launch(void* const* d_in, const int* in_sizes, int n_in,
                              void* d_out, int out_size, void* d_ws, size_t ws_size,
                              hipStream_t stream) {
    const float* x          = (const float*)d_in[0];
    const float* thresholds = (const float*)d_in[1];
    const float* table      = (const float*)d_in[2];
    const int*   chan_idx   = (const int*)d_in[3];
    const int*   offsets    = (const int*)d_in[4];
    float* out = (float*)d_out;

    // dynamic LDS > 64KB needs the opt-in attribute (idempotent, capture-safe)
    hipFuncSetAttribute((const void*)fern_fused,
                        hipFuncAttributeMaxDynamicSharedMemorySize, LDS_BYTES);

    dim3 grid(NN * 36);
    dim3 block(THREADS);
    fern_fused<<<grid, block, LDS_BYTES, stream>>>(x, thresholds, table,
                                                   chan_idx, offsets, out);
}